// Round 5
// baseline (469.184 us; speedup 1.0000x reference)
//
#include <hip/hip_runtime.h>

// ConvLSTM2D x2 encoder — fp16 MFMA implicit-GEMM, round 13.
// R12 model: LDS-BW-bound (per conv/block: 288KB DMA-w + 576KB B-read +
// 576KB A-read ~= 7us @ 85B/cy; 3 convs/CU ~= 20us heavy dispatch). Fix:
// amortize B over 2x M — 4-wave/256-thr blocks, 16x8 tile, M=128/wave
// (mt=8, acc[8][4]) + A dy-cache (A[0..9] read only at dy==0: 10 reads per
// 3 chunks vs 12). Conv LDS traffic 1440->816KB (-43%). acc128+A40+B16
// ~= 210 regs -> __launch_bounds__(256,2), 2 blocks/CU (LDS 75KB) keeps
// R12's 512-block backfill balance. Frame DMA = 4 ops -> vmcnt(4/0).

typedef _Float16 f16x8 __attribute__((ext_vector_type(8)));
typedef float f32x4 __attribute__((ext_vector_type(4)));

#define BHWF (8 * 64 * 64 * 64)
#define TSTRIDE 72                // LDS cell stride (fp16 units)
#define NCELL 180                 // 10 rows x 18 cols halo tile (16x8 px)

__device__ __forceinline__ float hsig(float x) {
    return fminf(fmaxf(fmaf(0.2f, x, 0.5f), 0.0f), 1.0f);
}

__device__ __forceinline__ float ftanh(float x) {
    float e = __expf(2.0f * x);
    return fmaf(-2.0f, __builtin_amdgcn_rcpf(e + 1.0f), 1.0f);
}

__device__ __forceinline__ ushort f2h(float f) {
    _Float16 h = (_Float16)f;     // v_cvt_f16_f32, RNE
    return __builtin_bit_cast(ushort, h);
}

// y=0..2: swizzle fp32 W[k=576][n=256] -> fp16 fragment-linear frames
//   (frame = tap*2+kc, 8192 ushorts each). y=3: Wx0 K=32-padded frames.
__global__ void prep_w(const float* __restrict__ s0, const float* __restrict__ s1,
                       const float* __restrict__ s2, const float* __restrict__ wx0,
                       ushort* __restrict__ d0, ushort* __restrict__ d1,
                       ushort* __restrict__ d2, ushort* __restrict__ dx0) {
    int o = blockIdx.x * 256 + threadIdx.x;
    if (blockIdx.y == 3) {
        if (o < 8192) {
            int e    = o & 7;
            int lane = (o >> 3) & 63;
            int g    = (o >> 9) & 3;
            int fq   = (o >> 11) & 3;
            int k = (lane >> 4) * 8 + e;
            int n = g * 64 + fq * 16 + (lane & 15);
            dx0[o] = (k < 9) ? f2h(wx0[k * 256 + n]) : (ushort)0;
        }
        return;
    }
    const float* s[3] = { s0, s1, s2 };
    ushort* d[3] = { d0, d1, d2 };
    int e    = o & 7;
    int lane = (o >> 3) & 63;
    int g    = (o >> 9) & 3;
    int fq   = (o >> 11) & 3;
    int kc   = (o >> 13) & 1;
    int tap  = o >> 14;
    int n = g * 64 + fq * 16 + (lane & 15);
    int k = tap * 64 + kc * 32 + (lane >> 4) * 8 + e;
    d[blockIdx.y][o] = f2h(s[blockIdx.y][k * 256 + n]);
}

// Stage 10x18 halo tile of fp16 [4096][64] image into LDS [cell][TSTRIDE].
__device__ __forceinline__ void stage(const ushort* __restrict__ src,
                                      ushort* __restrict__ tile,
                                      int y0, int x0, int tid) {
    for (int v = tid; v < NCELL * 8; v += 256) {
        int cell = v >> 3, j = v & 7;
        int r = cell / 18, cc = cell - r * 18;
        int y = y0 - 1 + r, xx = x0 - 1 + cc;
        uint4 dv = make_uint4(0u, 0u, 0u, 0u);
        if ((unsigned)y < 64u && (unsigned)xx < 64u)
            dv = ((const uint4*)src)[(size_t)((y << 6) + xx) * 8 + j];
        *(uint4*)&tile[cell * TSTRIDE + j * 8] = dv;
    }
}

__device__ __forceinline__ int frame_of(int c) {
    int kc = c / 9, r = c % 9, dxx = r / 3, dyy = r % 3;
    return (dyy * 3 + dxx) * 2 + kc;
}

// One frame = 16KB staged block-wide by 256 threads: 4 DMA ops x 16B/thread.
__device__ __forceinline__ void dma_frame(const ushort* __restrict__ src,
                                          ushort* __restrict__ dst, int tid) {
#pragma unroll
    for (int s = 0; s < 4; ++s)
        __builtin_amdgcn_global_load_lds(
            (const __attribute__((address_space(1))) unsigned int*)(src + s * 2048 + tid * 8),
            (__attribute__((address_space(3))) unsigned int*)(dst + s * 2048 + tid * 8),
            16, 0, 0);
}

// 3x3x64 conv, block tile 16x8 px, 4 waves (fq 4-way N), M=128/wave.
// A: 10-row column cached in regs, reloaded only at dy==0 (per kc,dx group).
// B: LDS 3-deep ring, 1 frame/chunk staged cooperatively (4 DMA ops),
// counted vmcnt(4), raw s_barrier. Chunk c: kc=c/9, dx=(c%9)/3, dy=c%3.
__device__ __forceinline__ void conv_stream(const ushort* __restrict__ tile,
                                            const ushort* __restrict__ WS,
                                            ushort* __restrict__ bbuf,
                                            f32x4 (&acc)[8][4],
                                            int fq, int lane, int tid) {
    const int colA = lane & 15;
    const int quad = (lane >> 4) & 3;
    __syncthreads();                       // prior readers of bbuf/xa done
    dma_frame(WS + (size_t)frame_of(0) * 8192, bbuf, tid);
    dma_frame(WS + (size_t)frame_of(1) * 8192, bbuf + 8192, tid);
    __asm__ volatile("s_waitcnt vmcnt(4)\ns_barrier" ::: "memory");
    f16x8 A[10];
#pragma unroll
    for (int c = 0; c < 18; ++c) {
        if (c <= 15)
            dma_frame(WS + (size_t)frame_of(c + 2) * 8192,
                      bbuf + ((c + 2) % 3) * 8192, tid);
        const int kc = c / 9, dx = (c % 9) / 3, dy = c % 3;
        if (dy == 0) {
#pragma unroll
            for (int r = 0; r < 10; ++r)
                A[r] = *(const f16x8*)&tile[(r * 18 + colA + dx) * TSTRIDE
                                            + kc * 32 + quad * 8];
        }
        const ushort* bp = bbuf + (c % 3) * 8192 + fq * 2048 + lane * 8;
        f16x8 B0 = *(const f16x8*)&bp[0];
        f16x8 B1 = *(const f16x8*)&bp[512];
        f16x8 B2 = *(const f16x8*)&bp[1024];
        f16x8 B3 = *(const f16x8*)&bp[1536];
#pragma unroll
        for (int mt = 0; mt < 8; ++mt) {
            acc[mt][0] = __builtin_amdgcn_mfma_f32_16x16x32_f16(A[mt + dy], B0, acc[mt][0], 0, 0, 0);
            acc[mt][1] = __builtin_amdgcn_mfma_f32_16x16x32_f16(A[mt + dy], B1, acc[mt][1], 0, 0, 0);
            acc[mt][2] = __builtin_amdgcn_mfma_f32_16x16x32_f16(A[mt + dy], B2, acc[mt][2], 0, 0, 0);
            acc[mt][3] = __builtin_amdgcn_mfma_f32_16x16x32_f16(A[mt + dy], B3, acc[mt][3], 0, 0, 0);
        }
        if (c <= 15)
            __asm__ volatile("s_waitcnt vmcnt(4)\ns_barrier" ::: "memory");
        else if (c == 16)
            __asm__ volatile("s_waitcnt vmcnt(0)\ns_barrier" ::: "memory");
        else
            __asm__ volatile("s_barrier" ::: "memory");
    }
}

// Merged step: z<8 -> L0 at time t, z>=8 -> L1 at time t-1 (independent work).
__global__ __launch_bounds__(256, 2) void step_merged(
    int l0_active, int l1_active, int last0, int last1,
    const float* __restrict__ x, const ushort* __restrict__ Wx0F,
    const ushort* __restrict__ Wh0S, const float* __restrict__ b0,
    const ushort* __restrict__ h0_prev, float* __restrict__ c0,
    ushort* __restrict__ h0_out, float* __restrict__ oh0, float* __restrict__ oc0,
    const ushort* __restrict__ xin, const ushort* __restrict__ Wx1S,
    const ushort* __restrict__ Wh1S, const float* __restrict__ b1,
    const ushort* __restrict__ h1_prev, float* __restrict__ c1,
    ushort* __restrict__ h1_out, float* __restrict__ oh1, float* __restrict__ oc1)
{
    __shared__ __align__(16) ushort tile[NCELL * TSTRIDE];   // 25,920 B
    __shared__ __align__(16) ushort bbuf[3 * 8192];          // 49,152 B ring
    ushort* xa = bbuf;                                       // alias: L0 im2col

    const int z = blockIdx.z;
    bool isL1; int b;
    if (l0_active && l1_active) { isL1 = (z >= 8); b = z & 7; }
    else                        { isL1 = (l1_active != 0); b = z; }

    const int tid = threadIdx.x;
    const int lane = tid & 63;
    const int fq = tid >> 6;            // wave id 0..3 = f quad (N split)
    const int colA = lane & 15;
    const int quad = (lane >> 4) & 3;
    const int x0 = blockIdx.x * 16, y0 = blockIdx.y * 8;
    const int blk = blockIdx.y * 4 + blockIdx.x;   // 0..31 px-tile id
    const int f = fq * 16 + colA;

    const ushort* h_prev = isL1 ? h1_prev : h0_prev;
    const float*  bias   = isL1 ? b1 : b0;
    float*        cbuf   = isL1 ? c1 : c0;
    ushort*       hout   = isL1 ? h1_out : h0_out;
    float* hf = isL1 ? (last1 ? oh1 : nullptr) : (last0 ? oh0 : nullptr);
    float* cf = isL1 ? (last1 ? oc1 : nullptr) : (last0 ? oc0 : nullptr);

    // ---- stage first A source ----
    if (!isL1) {
        const float* xs = x + (size_t)b * 40960;
        for (int idx = tid; idx < 4096; idx += 256) {
            int e = idx & 7, li = (idx >> 3) & 63, r = idx >> 9;   // r 0..7
            int ci = li & 15, qi = li >> 4;
            int k = qi * 8 + e;
            ushort val = 0;
            if (k < 9) {
                int dy = (k * 86) >> 8;
                int dx = k - dy * 3;
                int y = y0 + r + dy - 1, xx = x0 + ci + dx - 1;
                if ((unsigned)y < 64u && (unsigned)xx < 64u)
                    val = f2h(xs[(y << 6) + xx]);
            }
            xa[idx] = val;
        }
        if (h_prev) stage(h_prev + (size_t)b * 4096 * 64, tile, y0, x0, tid);
    } else {
        stage(xin + (size_t)b * 4096 * 64, tile, y0, x0, tid);
    }
    __syncthreads();

    // ---- init accumulators with bias ----
    f32x4 acc[8][4];
#pragma unroll
    for (int g = 0; g < 4; ++g) {
        float bv = bias[g * 64 + f];
#pragma unroll
        for (int mt = 0; mt < 8; ++mt) {
            acc[mt][g][0] = bv; acc[mt][g][1] = bv;
            acc[mt][g][2] = bv; acc[mt][g][3] = bv;
        }
    }

    if (!isL1) {
        // x-conv via MFMA (K=32-padded Wx0 frames); xa lives in bbuf[0]
        f16x8 xb[4];
#pragma unroll
        for (int g = 0; g < 4; ++g)
            xb[g] = *(const f16x8*)&Wx0F[((fq * 4 + g) * 64 + lane) * 8];
#pragma unroll
        for (int mt = 0; mt < 8; ++mt) {
            f16x8 xaf = *(const f16x8*)&xa[mt * 512 + lane * 8];
#pragma unroll
            for (int g = 0; g < 4; ++g)
                acc[mt][g] = __builtin_amdgcn_mfma_f32_16x16x32_f16(
                    xaf, xb[g], acc[mt][g], 0, 0, 0);
        }
        if (h_prev) conv_stream(tile, Wh0S, bbuf, acc, fq, lane, tid);
    } else {
        conv_stream(tile, Wx1S, bbuf, acc, fq, lane, tid);
        if (h_prev) {
            __syncthreads();
            stage(h_prev + (size_t)b * 4096 * 64, tile, y0, x0, tid);
            __syncthreads();
            conv_stream(tile, Wh1S, bbuf, acc, fq, lane, tid);
        }
    }

    // ---- LSTM pointwise epilogue ----
    // cbuf private layout (lane-linear): ((((b*32+blk)*4+fq)*8+mt)*4+reg)*64+lane
#pragma unroll
    for (int mt = 0; mt < 8; ++mt) {
        const int y = y0 + mt;
#pragma unroll
        for (int reg = 0; reg < 4; ++reg) {
            const int xx = x0 + quad * 4 + reg;
            const size_t cidx = (((((size_t)b * 32 + blk) * 4 + fq) * 8 + mt) * 4
                                 + reg) * 64 + lane;
            const size_t pidx = ((size_t)b * 4096 + (y << 6) + xx) * 64 + f;
            float cp = h_prev ? cbuf[cidx] : 0.f;
            float iv = hsig(acc[mt][0][reg]);
            float fv = hsig(acc[mt][1][reg]);
            float gv = ftanh(acc[mt][2][reg]);
            float ov = hsig(acc[mt][3][reg]);
            float cn = fmaf(fv, cp, iv * gv);
            float hn = ov * ftanh(cn);
            cbuf[cidx] = cn;
            hout[pidx] = f2h(hn);
            if (hf) { hf[pidx] = hn; cf[pidx] = cn; }
        }
    }
}

extern "C" void kernel_launch(void* const* d_in, const int* in_sizes, int n_in,
                              void* d_out, int out_size, void* d_ws, size_t ws_size,
                              hipStream_t stream) {
    const float* x   = (const float*)d_in[0];
    const float* Wx0 = (const float*)d_in[1];
    const float* Wh0 = (const float*)d_in[2];
    const float* b0  = (const float*)d_in[3];
    const float* Wx1 = (const float*)d_in[4];
    const float* Wh1 = (const float*)d_in[5];
    const float* b1  = (const float*)d_in[6];
    float* out = (float*)d_out;
    char* ws = (char*)d_ws;

    ushort* h0buf[2] = { (ushort*)ws, (ushort*)(ws + 4u * 1024 * 1024) };
    ushort* h1buf[2] = { (ushort*)(ws + 8u * 1024 * 1024), (ushort*)(ws + 12u * 1024 * 1024) };
    float* c0 = (float*)(ws + 16u * 1024 * 1024);
    float* c1 = (float*)(ws + 24u * 1024 * 1024);
    ushort* Wh0S = (ushort*)(ws + 32u * 1024 * 1024);
    ushort* Wx1S = Wh0S + 147456;
    ushort* Wh1S = Wx1S + 147456;
    ushort* Wx0F = Wh1S + 147456;

    prep_w<<<dim3(576, 4), 256, 0, stream>>>(Wh0, Wx1, Wh1, Wx0,
                                             Wh0S, Wx1S, Wh1S, Wx0F);

    for (int t = 0; t <= 10; ++t) {
        const int has0 = (t < 10), has1 = (t >= 1);
        const int s = t - 1;
        const int tx = has0 ? t : 9;
        dim3 grid(4, 8, (has0 && has1) ? 16 : 8);
        step_merged<<<grid, 256, 0, stream>>>(
            has0, has1, (t == 9), (s == 9),
            x + (size_t)tx * 4096, Wx0F,
            (t >= 1) ? Wh0S : nullptr, b0,
            (t >= 1 && has0) ? h0buf[(t - 1) & 1] : nullptr, c0,
            h0buf[t & 1], out, out + BHWF,
            has1 ? h0buf[s & 1] : nullptr, Wx1S,
            Wh1S, b1,
            (s >= 1) ? h1buf[(s - 1) & 1] : nullptr, c1,
            h1buf[s & 1], out + 2 * (size_t)BHWF, out + 3 * (size_t)BHWF);
    }
}

// Round 6
// 383.029 us; speedup vs baseline: 1.2249x; 1.2249x over previous
//
#include <hip/hip_runtime.h>

// ConvLSTM2D x2 encoder — fp16 MFMA implicit-GEMM, round 14.
// R13 post-mortem: acc[8][4]+A[10] blew the 256-VGPR cap -> spill ops inside
// the counted-vmcnt region (scratch uses vmcnt!) -> stale B frames (absmax
// 0.0156->0.0596) + scratch traffic (391->469us). Rule: the counted-vmcnt
// ring is only sound with zero other vmem ops in the loop == low reg
// pressure. This round: exact R12 structure (known-good 391us / 0.0156,
// VGPR 64, 2 blk/CU) + ONE lever: partial A-row cache C1..C4 (+16 VGPR,
// static refs only, loop fully unrolled). Per (kc,dx) group: 6 A ds_reads
// vs 12. Conv LDS traffic 1440->1152KB (-20%). Bit-identical math to R12.

typedef _Float16 f16x8 __attribute__((ext_vector_type(8)));
typedef float f32x4 __attribute__((ext_vector_type(4)));

#define BHWF (8 * 64 * 64 * 64)
#define TSTRIDE 72                // LDS cell stride (fp16 units)
#define NCELL 180                 // 10 rows x 18 cols halo tile (16x8 px)

__device__ __forceinline__ float hsig(float x) {
    return fminf(fmaxf(fmaf(0.2f, x, 0.5f), 0.0f), 1.0f);
}

__device__ __forceinline__ float ftanh(float x) {
    float e = __expf(2.0f * x);
    return fmaf(-2.0f, __builtin_amdgcn_rcpf(e + 1.0f), 1.0f);
}

__device__ __forceinline__ ushort f2h(float f) {
    _Float16 h = (_Float16)f;     // v_cvt_f16_f32, RNE
    return __builtin_bit_cast(ushort, h);
}

// y=0..2: swizzle fp32 W[k=576][n=256] -> fp16 fragment-linear frames
//   (frame = tap*2+kc, 8192 ushorts each). y=3: Wx0 K=32-padded frames.
__global__ void prep_w(const float* __restrict__ s0, const float* __restrict__ s1,
                       const float* __restrict__ s2, const float* __restrict__ wx0,
                       ushort* __restrict__ d0, ushort* __restrict__ d1,
                       ushort* __restrict__ d2, ushort* __restrict__ dx0) {
    int o = blockIdx.x * 256 + threadIdx.x;
    if (blockIdx.y == 3) {
        if (o < 8192) {
            int e    = o & 7;
            int lane = (o >> 3) & 63;
            int g    = (o >> 9) & 3;
            int fq   = (o >> 11) & 3;
            int k = (lane >> 4) * 8 + e;
            int n = g * 64 + fq * 16 + (lane & 15);
            dx0[o] = (k < 9) ? f2h(wx0[k * 256 + n]) : (ushort)0;
        }
        return;
    }
    const float* s[3] = { s0, s1, s2 };
    ushort* d[3] = { d0, d1, d2 };
    int e    = o & 7;
    int lane = (o >> 3) & 63;
    int g    = (o >> 9) & 3;
    int fq   = (o >> 11) & 3;
    int kc   = (o >> 13) & 1;
    int tap  = o >> 14;
    int n = g * 64 + fq * 16 + (lane & 15);
    int k = tap * 64 + kc * 32 + (lane >> 4) * 8 + e;
    d[blockIdx.y][o] = f2h(s[blockIdx.y][k * 256 + n]);
}

// Stage 10x18 halo tile of fp16 [4096][64] image into LDS [cell][TSTRIDE].
__device__ __forceinline__ void stage(const ushort* __restrict__ src,
                                      ushort* __restrict__ tile,
                                      int y0, int x0, int tid) {
    for (int v = tid; v < NCELL * 8; v += 512) {
        int cell = v >> 3, j = v & 7;
        int r = cell / 18, cc = cell - r * 18;
        int y = y0 - 1 + r, xx = x0 - 1 + cc;
        uint4 dv = make_uint4(0u, 0u, 0u, 0u);
        if ((unsigned)y < 64u && (unsigned)xx < 64u)
            dv = ((const uint4*)src)[(size_t)((y << 6) + xx) * 8 + j];
        *(uint4*)&tile[cell * TSTRIDE + j * 8] = dv;
    }
}

__device__ __forceinline__ int frame_of(int c) {
    int kc = c / 9, r = c % 9, dxx = r / 3, dyy = r % 3;
    return (dyy * 3 + dxx) * 2 + kc;
}

// One frame = 16KB staged block-wide by 512 threads: 2 DMA ops x 16B/thread.
__device__ __forceinline__ void dma_frame(const ushort* __restrict__ src,
                                          ushort* __restrict__ dst, int tid) {
    __builtin_amdgcn_global_load_lds(
        (const __attribute__((address_space(1))) unsigned int*)(src + tid * 8),
        (__attribute__((address_space(3))) unsigned int*)(dst + tid * 8),
        16, 0, 0);
    __builtin_amdgcn_global_load_lds(
        (const __attribute__((address_space(1))) unsigned int*)(src + 4096 + tid * 8),
        (__attribute__((address_space(3))) unsigned int*)(dst + 4096 + tid * 8),
        16, 0, 0);
}

// 3x3x64 conv, block tile 16x8 px, 8 waves (mw 2-way M, fq 4-way N).
// B: LDS 3-deep ring, 1 frame/chunk staged cooperatively (2 DMA ops),
// counted vmcnt(2), raw s_barrier. Chunk c: kc=c/9, dx=(c%9)/3, dy=c%3.
// A: rows mw*4+{1..4} cached in C1..C4 per (kc,dx) group; rows 0/5 read
// fresh at dy==0/2. 6 A ds_reads per group vs 12 (all refs static; the
// c-loop is fully unrolled so branches fold and no runtime indexing).
__device__ __forceinline__ void conv_stream(const ushort* __restrict__ tile,
                                            const ushort* __restrict__ WS,
                                            ushort* __restrict__ bbuf,
                                            f32x4 (&acc)[4][4],
                                            int fq, int mw, int lane, int tid) {
    const int colA = lane & 15;
    const int quad = (lane >> 4) & 3;
    __syncthreads();                       // prior readers of bbuf/xa done
    dma_frame(WS + (size_t)frame_of(0) * 8192, bbuf, tid);
    dma_frame(WS + (size_t)frame_of(1) * 8192, bbuf + 8192, tid);
    __asm__ volatile("s_waitcnt vmcnt(2)\ns_barrier" ::: "memory");
    f16x8 C1, C2, C3, C4;
#pragma unroll
    for (int c = 0; c < 18; ++c) {
        if (c <= 15)
            dma_frame(WS + (size_t)frame_of(c + 2) * 8192,
                      bbuf + ((c + 2) % 3) * 8192, tid);
        const int kc = c / 9, dx = (c % 9) / 3, dy = c % 3;
        const ushort* arow = &tile[((mw * 4) * 18 + colA + dx) * TSTRIDE
                                   + kc * 32 + quad * 8];
        f16x8 m0, m1, m2, m3;
        if (dy == 0) {
            m0 = *(const f16x8*)&arow[0 * 18 * TSTRIDE];
            C1 = *(const f16x8*)&arow[1 * 18 * TSTRIDE];
            C2 = *(const f16x8*)&arow[2 * 18 * TSTRIDE];
            C3 = *(const f16x8*)&arow[3 * 18 * TSTRIDE];
            m1 = C1; m2 = C2; m3 = C3;
        } else if (dy == 1) {
            C4 = *(const f16x8*)&arow[4 * 18 * TSTRIDE];
            m0 = C1; m1 = C2; m2 = C3; m3 = C4;
        } else {
            f16x8 a5 = *(const f16x8*)&arow[5 * 18 * TSTRIDE];
            m0 = C2; m1 = C3; m2 = C4; m3 = a5;
        }
        const ushort* bp = bbuf + (c % 3) * 8192 + fq * 2048 + lane * 8;
        f16x8 B0 = *(const f16x8*)&bp[0];
        f16x8 B1 = *(const f16x8*)&bp[512];
        f16x8 B2 = *(const f16x8*)&bp[1024];
        f16x8 B3 = *(const f16x8*)&bp[1536];
        acc[0][0] = __builtin_amdgcn_mfma_f32_16x16x32_f16(m0, B0, acc[0][0], 0, 0, 0);
        acc[0][1] = __builtin_amdgcn_mfma_f32_16x16x32_f16(m0, B1, acc[0][1], 0, 0, 0);
        acc[0][2] = __builtin_amdgcn_mfma_f32_16x16x32_f16(m0, B2, acc[0][2], 0, 0, 0);
        acc[0][3] = __builtin_amdgcn_mfma_f32_16x16x32_f16(m0, B3, acc[0][3], 0, 0, 0);
        acc[1][0] = __builtin_amdgcn_mfma_f32_16x16x32_f16(m1, B0, acc[1][0], 0, 0, 0);
        acc[1][1] = __builtin_amdgcn_mfma_f32_16x16x32_f16(m1, B1, acc[1][1], 0, 0, 0);
        acc[1][2] = __builtin_amdgcn_mfma_f32_16x16x32_f16(m1, B2, acc[1][2], 0, 0, 0);
        acc[1][3] = __builtin_amdgcn_mfma_f32_16x16x32_f16(m1, B3, acc[1][3], 0, 0, 0);
        acc[2][0] = __builtin_amdgcn_mfma_f32_16x16x32_f16(m2, B0, acc[2][0], 0, 0, 0);
        acc[2][1] = __builtin_amdgcn_mfma_f32_16x16x32_f16(m2, B1, acc[2][1], 0, 0, 0);
        acc[2][2] = __builtin_amdgcn_mfma_f32_16x16x32_f16(m2, B2, acc[2][2], 0, 0, 0);
        acc[2][3] = __builtin_amdgcn_mfma_f32_16x16x32_f16(m2, B3, acc[2][3], 0, 0, 0);
        acc[3][0] = __builtin_amdgcn_mfma_f32_16x16x32_f16(m3, B0, acc[3][0], 0, 0, 0);
        acc[3][1] = __builtin_amdgcn_mfma_f32_16x16x32_f16(m3, B1, acc[3][1], 0, 0, 0);
        acc[3][2] = __builtin_amdgcn_mfma_f32_16x16x32_f16(m3, B2, acc[3][2], 0, 0, 0);
        acc[3][3] = __builtin_amdgcn_mfma_f32_16x16x32_f16(m3, B3, acc[3][3], 0, 0, 0);
        if (c <= 15)
            __asm__ volatile("s_waitcnt vmcnt(2)\ns_barrier" ::: "memory");
        else if (c == 16)
            __asm__ volatile("s_waitcnt vmcnt(0)\ns_barrier" ::: "memory");
        else
            __asm__ volatile("s_barrier" ::: "memory");
    }
}

// Merged step: z<8 -> L0 at time t, z>=8 -> L1 at time t-1 (independent work).
__global__ __launch_bounds__(512, 4) void step_merged(
    int l0_active, int l1_active, int last0, int last1,
    const float* __restrict__ x, const ushort* __restrict__ Wx0F,
    const ushort* __restrict__ Wh0S, const float* __restrict__ b0,
    const ushort* __restrict__ h0_prev, float* __restrict__ c0,
    ushort* __restrict__ h0_out, float* __restrict__ oh0, float* __restrict__ oc0,
    const ushort* __restrict__ xin, const ushort* __restrict__ Wx1S,
    const ushort* __restrict__ Wh1S, const float* __restrict__ b1,
    const ushort* __restrict__ h1_prev, float* __restrict__ c1,
    ushort* __restrict__ h1_out, float* __restrict__ oh1, float* __restrict__ oc1)
{
    __shared__ __align__(16) ushort tile[NCELL * TSTRIDE];   // 25,920 B
    __shared__ __align__(16) ushort bbuf[3 * 8192];          // 49,152 B ring
    ushort* xa = bbuf;                                       // alias: L0 im2col

    const int z = blockIdx.z;
    bool isL1; int b;
    if (l0_active && l1_active) { isL1 = (z >= 8); b = z & 7; }
    else                        { isL1 = (l1_active != 0); b = z; }

    const int tid = threadIdx.x;
    const int lane = tid & 63;
    const int w = tid >> 6;             // wave id 0..7
    const int fq = w & 3;               // f quad (N split)
    const int mw = w >> 2;              // 4-row band (M split), 0..1
    const int colA = lane & 15;
    const int quad = (lane >> 4) & 3;
    const int x0 = blockIdx.x * 16, y0 = blockIdx.y * 8;
    const int blk = blockIdx.y * 4 + blockIdx.x;   // 0..31 px-tile id
    const int f = fq * 16 + colA;

    const ushort* h_prev = isL1 ? h1_prev : h0_prev;
    const float*  bias   = isL1 ? b1 : b0;
    float*        cbuf   = isL1 ? c1 : c0;
    ushort*       hout   = isL1 ? h1_out : h0_out;
    float* hf = isL1 ? (last1 ? oh1 : nullptr) : (last0 ? oh0 : nullptr);
    float* cf = isL1 ? (last1 ? oc1 : nullptr) : (last0 ? oc0 : nullptr);

    // ---- stage first A source ----
    if (!isL1) {
        const float* xs = x + (size_t)b * 40960;
        for (int idx = tid; idx < 4096; idx += 512) {
            int e = idx & 7, li = (idx >> 3) & 63, r = idx >> 9;   // r 0..7
            int ci = li & 15, qi = li >> 4;
            int k = qi * 8 + e;
            ushort val = 0;
            if (k < 9) {
                int dy = (k * 86) >> 8;
                int dx = k - dy * 3;
                int y = y0 + r + dy - 1, xx = x0 + ci + dx - 1;
                if ((unsigned)y < 64u && (unsigned)xx < 64u)
                    val = f2h(xs[(y << 6) + xx]);
            }
            xa[idx] = val;
        }
        if (h_prev) stage(h_prev + (size_t)b * 4096 * 64, tile, y0, x0, tid);
    } else {
        stage(xin + (size_t)b * 4096 * 64, tile, y0, x0, tid);
    }
    __syncthreads();

    // ---- init accumulators with bias ----
    f32x4 acc[4][4];
#pragma unroll
    for (int g = 0; g < 4; ++g) {
        float bv = bias[g * 64 + f];
#pragma unroll
        for (int mt = 0; mt < 4; ++mt) {
            acc[mt][g][0] = bv; acc[mt][g][1] = bv;
            acc[mt][g][2] = bv; acc[mt][g][3] = bv;
        }
    }

    if (!isL1) {
        // x-conv via MFMA (K=32-padded Wx0 frames); xa lives in bbuf[0]
        f16x8 xb[4];
#pragma unroll
        for (int g = 0; g < 4; ++g)
            xb[g] = *(const f16x8*)&Wx0F[((fq * 4 + g) * 64 + lane) * 8];
#pragma unroll
        for (int mt = 0; mt < 4; ++mt) {
            f16x8 xaf = *(const f16x8*)&xa[(mw * 4 + mt) * 512 + lane * 8];
#pragma unroll
            for (int g = 0; g < 4; ++g)
                acc[mt][g] = __builtin_amdgcn_mfma_f32_16x16x32_f16(
                    xaf, xb[g], acc[mt][g], 0, 0, 0);
        }
        if (h_prev) conv_stream(tile, Wh0S, bbuf, acc, fq, mw, lane, tid);
    } else {
        conv_stream(tile, Wx1S, bbuf, acc, fq, mw, lane, tid);
        if (h_prev) {
            __syncthreads();
            stage(h_prev + (size_t)b * 4096 * 64, tile, y0, x0, tid);
            __syncthreads();
            conv_stream(tile, Wh1S, bbuf, acc, fq, mw, lane, tid);
        }
    }

    // ---- LSTM pointwise epilogue ----
    // cbuf private layout (lane-linear): ((((b*32+blk)*8+w)*4+mt)*4+reg)*64+lane
#pragma unroll
    for (int mt = 0; mt < 4; ++mt) {
        const int y = y0 + mw * 4 + mt;
#pragma unroll
        for (int reg = 0; reg < 4; ++reg) {
            const int xx = x0 + quad * 4 + reg;
            const size_t cidx = (((((size_t)b * 32 + blk) * 8 + w) * 4 + mt) * 4
                                 + reg) * 64 + lane;
            const size_t pidx = ((size_t)b * 4096 + (y << 6) + xx) * 64 + f;
            float cp = h_prev ? cbuf[cidx] : 0.f;
            float iv = hsig(acc[mt][0][reg]);
            float fv = hsig(acc[mt][1][reg]);
            float gv = ftanh(acc[mt][2][reg]);
            float ov = hsig(acc[mt][3][reg]);
            float cn = fmaf(fv, cp, iv * gv);
            float hn = ov * ftanh(cn);
            cbuf[cidx] = cn;
            hout[pidx] = f2h(hn);
            if (hf) { hf[pidx] = hn; cf[pidx] = cn; }
        }
    }
}

extern "C" void kernel_launch(void* const* d_in, const int* in_sizes, int n_in,
                              void* d_out, int out_size, void* d_ws, size_t ws_size,
                              hipStream_t stream) {
    const float* x   = (const float*)d_in[0];
    const float* Wx0 = (const float*)d_in[1];
    const float* Wh0 = (const float*)d_in[2];
    const float* b0  = (const float*)d_in[3];
    const float* Wx1 = (const float*)d_in[4];
    const float* Wh1 = (const float*)d_in[5];
    const float* b1  = (const float*)d_in[6];
    float* out = (float*)d_out;
    char* ws = (char*)d_ws;

    ushort* h0buf[2] = { (ushort*)ws, (ushort*)(ws + 4u * 1024 * 1024) };
    ushort* h1buf[2] = { (ushort*)(ws + 8u * 1024 * 1024), (ushort*)(ws + 12u * 1024 * 1024) };
    float* c0 = (float*)(ws + 16u * 1024 * 1024);
    float* c1 = (float*)(ws + 24u * 1024 * 1024);
    ushort* Wh0S = (ushort*)(ws + 32u * 1024 * 1024);
    ushort* Wx1S = Wh0S + 147456;
    ushort* Wh1S = Wx1S + 147456;
    ushort* Wx0F = Wh1S + 147456;

    prep_w<<<dim3(576, 4), 256, 0, stream>>>(Wh0, Wx1, Wh1, Wx0,
                                             Wh0S, Wx1S, Wh1S, Wx0F);

    for (int t = 0; t <= 10; ++t) {
        const int has0 = (t < 10), has1 = (t >= 1);
        const int s = t - 1;
        const int tx = has0 ? t : 9;
        dim3 grid(4, 8, (has0 && has1) ? 16 : 8);
        step_merged<<<grid, 512, 0, stream>>>(
            has0, has1, (t == 9), (s == 9),
            x + (size_t)tx * 4096, Wx0F,
            (t >= 1) ? Wh0S : nullptr, b0,
            (t >= 1 && has0) ? h0buf[(t - 1) & 1] : nullptr, c0,
            h0buf[t & 1], out, out + BHWF,
            has1 ? h0buf[s & 1] : nullptr, Wx1S,
            Wh1S, b1,
            (s >= 1) ? h1buf[(s - 1) & 1] : nullptr, c1,
            h1buf[s & 1], out + 2 * (size_t)BHWF, out + 3 * (size_t)BHWF);
    }
}